// Round 4
// baseline (30.660 us; speedup 1.0000x reference)
//
#include <hip/hip_runtime.h>

// MemoryLayer: B=4, S=2048, IN_DIM=1024, OUT_DIM=2048, K=64, CHUNK=16,
// OUT_CHUNK=32, TAU=16, N_BUCKETS=65536, T=1.0
constexpr int IN_DIM    = 1024;
constexpr int OUT_DIM   = 2048;
constexpr int K         = 64;
constexpr int CHUNK     = 16;
constexpr int OUT_CHUNK = 32;
constexpr int ROWS      = 4 * 2048;   // B*S
constexpr int NBUCKETS  = 65536;

__global__ __launch_bounds__(256) void
memlayer_kernel(const float* __restrict__ x,
                const float* __restrict__ tables,
                float* __restrict__ out)
{
    const int g    = blockIdx.x * 256 + threadIdx.x;
    const int row  = g >> 6;           // one wave per x-row
    const int lane = threadIdx.x & 63; // = k in phase 1

    const float* xr = x + (size_t)row * IN_DIM + lane * CHUNK;

    // Phase 1: each lane computes hash h and gate p for its own k = lane.
    float4 x0 = reinterpret_cast<const float4*>(xr)[0];
    float4 x1 = reinterpret_cast<const float4*>(xr)[1];
    float4 x2 = reinterpret_cast<const float4*>(xr)[2];
    float4 x3 = reinterpret_cast<const float4*>(xr)[3];

    unsigned h = 0;
    float denom = 1.0f;
#define PROC(v, idx)                                              \
    do {                                                          \
        h |= ((v) >= 0.0f ? 1u : 0u) << (15 - (idx));             \
        denom *= 1.0f + __expf(-2.0f * (v));                      \
    } while (0)
    PROC(x0.x,  0); PROC(x0.y,  1); PROC(x0.z,  2); PROC(x0.w,  3);
    PROC(x1.x,  4); PROC(x1.y,  5); PROC(x1.z,  6); PROC(x1.w,  7);
    PROC(x2.x,  8); PROC(x2.y,  9); PROC(x2.z, 10); PROC(x2.w, 11);
    PROC(x3.x, 12); PROC(x3.y, 13); PROC(x3.z, 14); PROC(x3.w, 15);
#undef PROC
    const float p = 1.0f / denom;   // inf -> 0, correct underflow limit

    // Phase 2: 8 lanes cooperate per table row. sub = 16B segment index.
    const int kg  = lane >> 3;      // which k within this pass
    const int sub = lane & 7;       // float4 index within the 32-float row

    float4* orow = reinterpret_cast<float4*>(out + (size_t)row * OUT_DIM);

    // Issue ALL shuffles + gathers first (max MLP), then scale+store.
    float4 t[8];
    float  pk[8];
#pragma unroll
    for (int pass = 0; pass < 8; ++pass) {
        const int src = pass * 8 + kg;                 // lane holding (h,p) for k=src
        const unsigned hk = (unsigned)__shfl((int)h, src, 64);
        pk[pass] = __shfl(p, src, 64);
        const float4* trow = reinterpret_cast<const float4*>(
            tables + ((size_t)src * NBUCKETS + (size_t)hk) * OUT_CHUNK);
        t[pass] = trow[sub];                           // 8 lanes -> one 128B line
    }
#pragma unroll
    for (int pass = 0; pass < 8; ++pass) {
        float4 o;
        o.x = t[pass].x * pk[pass];
        o.y = t[pass].y * pk[pass];
        o.z = t[pass].z * pk[pass];
        o.w = t[pass].w * pk[pass];
        // float4 index = src*8 + sub = (pass*8+kg)*8 + (lane&7) = pass*64 + lane
        orow[pass * 64 + lane] = o;
    }
}

extern "C" void kernel_launch(void* const* d_in, const int* in_sizes, int n_in,
                              void* d_out, int out_size, void* d_ws, size_t ws_size,
                              hipStream_t stream)
{
    const float* x      = (const float*)d_in[0];
    const float* tables = (const float*)d_in[1];
    float*       out    = (float*)d_out;

    const int total  = ROWS * K;          // 524288 threads
    const int block  = 256;
    const int grid   = total / block;     // 2048 blocks

    memlayer_kernel<<<grid, block, 0, stream>>>(x, tables, out);
}

// Round 5
// 30.278 us; speedup vs baseline: 1.0126x; 1.0126x over previous
//
#include <hip/hip_runtime.h>

// MemoryLayer: B=4, S=2048, IN_DIM=1024, OUT_DIM=2048, K=64, CHUNK=16,
// OUT_CHUNK=32, TAU=16, N_BUCKETS=65536, T=1.0
constexpr int IN_DIM    = 1024;
constexpr int OUT_DIM   = 2048;
constexpr int K         = 64;
constexpr int CHUNK     = 16;
constexpr int OUT_CHUNK = 32;
constexpr int ROWS      = 4 * 2048;   // B*S
constexpr int NBUCKETS  = 65536;

// One thread per (row, k, seg): seg = which 16B segment of the 128B table row.
// 8 consecutive lanes cooperate on one (row,k): each loads 2 floats of the
// 16-float chunk, computes partial hash/product, butterfly-reduces, then does
// exactly one 16B gather + one 16B store. Max TLP, ~30 VGPR, full occupancy.
__global__ __launch_bounds__(256) void
memlayer_kernel(const float* __restrict__ x,
                const float* __restrict__ tables,
                float* __restrict__ out)
{
    const int g   = blockIdx.x * 256 + threadIdx.x;
    const int seg = g & 7;        // float4 index within table row
    const int q   = g >> 3;       // (row,k) pair id: q = row*64 + k
    const int k   = q & 63;

    // x chunk base = row*IN_DIM + k*CHUNK = q*CHUNK (since IN_DIM = 64*CHUNK)
    const float2 xv = *reinterpret_cast<const float2*>(
        x + (size_t)q * CHUNK + seg * 2);

    // partial hash: element idx0 = 2*seg (weight 15-2*seg), idx1 = 2*seg+1
    unsigned h = ((xv.x >= 0.0f ? 1u : 0u) << (15 - 2 * seg))
               | ((xv.y >= 0.0f ? 1u : 0u) << (14 - 2 * seg));
    float denom = (1.0f + __expf(-2.0f * xv.x)) * (1.0f + __expf(-2.0f * xv.y));

    // 8-lane butterfly reduce (lanes seg=0..7 share one (row,k))
    h |= (unsigned)__shfl_xor((int)h, 1, 64);  denom *= __shfl_xor(denom, 1, 64);
    h |= (unsigned)__shfl_xor((int)h, 2, 64);  denom *= __shfl_xor(denom, 2, 64);
    h |= (unsigned)__shfl_xor((int)h, 4, 64);  denom *= __shfl_xor(denom, 4, 64);

    const float p = 1.0f / denom;   // inf -> 0, correct underflow limit

    const float4 t = reinterpret_cast<const float4*>(
        tables + ((size_t)k * NBUCKETS + (size_t)h) * OUT_CHUNK)[seg];

    float4 o;
    o.x = t.x * p; o.y = t.y * p; o.z = t.z * p; o.w = t.w * p;
    // out float4 index = q*8 + seg -> contiguous 1024B per wave
    reinterpret_cast<float4*>(out)[(size_t)q * 8 + seg] = o;
}

extern "C" void kernel_launch(void* const* d_in, const int* in_sizes, int n_in,
                              void* d_out, int out_size, void* d_ws, size_t ws_size,
                              hipStream_t stream)
{
    const float* x      = (const float*)d_in[0];
    const float* tables = (const float*)d_in[1];
    float*       out    = (float*)d_out;

    const int total = ROWS * K * 8;       // 4,194,304 threads
    const int block = 256;
    const int grid  = total / block;      // 16384 blocks

    memlayer_kernel<<<grid, block, 0, stream>>>(x, tables, out);
}